// Round 1
// baseline (654.778 us; speedup 1.0000x reference)
//
#include <hip/hip_runtime.h>

typedef _Float16 h8 __attribute__((ext_vector_type(8)));
typedef float f4 __attribute__((ext_vector_type(4)));

#define H 128
#define HH2 256
#define M_OUT 2048

__device__ __forceinline__ float u2f_lo(unsigned v) {
  union { unsigned short s; _Float16 h; } c; c.s = (unsigned short)(v & 0xffffu); return (float)c.h;
}
__device__ __forceinline__ float u2f_hi(unsigned v) {
  union { unsigned short s; _Float16 h; } c; c.s = (unsigned short)(v >> 16); return (float)c.h;
}

// ---- weight prep: transpose + fp16 convert. mat 0 = W_embed, 1+2l = Wtop_l, 2+2l = Wbot_l
__global__ void prep_weights(const float* __restrict__ We, const float* __restrict__ Wm,
                             _Float16* __restrict__ WtAll) {
  int gid = blockIdx.x * 256 + threadIdx.x;
  if (gid >= 7 * 16384) return;
  int m = gid >> 14, rem = gid & 16383, c = rem >> 7, k = rem & 127;
  float v;
  if (m == 0) v = We[k * H + c];
  else {
    int l = (m - 1) >> 1, bot = (m - 1) & 1;
    v = Wm[l * (2 * H * H) + (bot * H + k) * H + c];
  }
  WtAll[m * 16384 + c * H + k] = (_Float16)v;   // row = out-col, contiguous k
}

__global__ void cvt_f16(const float* __restrict__ x, _Float16* __restrict__ xb, int n) {
  int i = (blockIdx.x * 256 + threadIdx.x) * 4;
  if (i >= n) return;
  float4 v = *(const float4*)(x + i);
  union { _Float16 h[4]; uint2 u; } o;
  o.h[0] = (_Float16)v.x; o.h[1] = (_Float16)v.y; o.h[2] = (_Float16)v.z; o.h[3] = (_Float16)v.w;
  *(uint2*)(xb + i) = o.u;
}

// ---- CSR build
__global__ void count_k(const int* __restrict__ ei, int E, int* __restrict__ cnt) {
  int e = blockIdx.x * 256 + threadIdx.x;
  if (e < E) atomicAdd(&cnt[ei[E + e]], 1);
}

__global__ void sc1(const int* __restrict__ cnt, int* __restrict__ bsum, int N) {
  __shared__ int red[256];
  int t = threadIdx.x;
  int base = blockIdx.x * 1024 + t * 4;
  int s = 0;
  if (base + 3 < N) { int4 v = *(const int4*)(cnt + base); s = v.x + v.y + v.z + v.w; }
  else { for (int i = 0; i < 4; ++i) if (base + i < N) s += cnt[base + i]; }
  red[t] = s; __syncthreads();
  for (int off = 128; off; off >>= 1) { if (t < off) red[t] += red[t + off]; __syncthreads(); }
  if (t == 0) bsum[blockIdx.x] = red[0];
}

__global__ void sc2(int* __restrict__ bsum, int nblk) {
  __shared__ int sm[128];
  int t = threadIdx.x;
  sm[t] = (t < nblk) ? bsum[t] : 0; __syncthreads();
  for (int off = 1; off < 128; off <<= 1) {
    int add = (t >= off) ? sm[t - off] : 0; __syncthreads();
    sm[t] += add; __syncthreads();
  }
  if (t < nblk) bsum[t] = (t == 0) ? 0 : sm[t - 1];   // exclusive
}

__global__ void sc3(const int* __restrict__ cnt, const int* __restrict__ boff,
                    int* __restrict__ row_ptr, int N, int E) {
  __shared__ int sm[256];
  int t = threadIdx.x;
  int base = blockIdx.x * 1024 + t * 4;
  int v0 = (base + 0 < N) ? cnt[base + 0] : 0;
  int v1 = (base + 1 < N) ? cnt[base + 1] : 0;
  int v2 = (base + 2 < N) ? cnt[base + 2] : 0;
  int v3 = (base + 3 < N) ? cnt[base + 3] : 0;
  sm[t] = v0 + v1 + v2 + v3; __syncthreads();
  for (int off = 1; off < 256; off <<= 1) {
    int add = (t >= off) ? sm[t - off] : 0; __syncthreads();
    sm[t] += add; __syncthreads();
  }
  int prefix = boff[blockIdx.x] + ((t > 0) ? sm[t - 1] : 0);
  if (base + 0 < N) row_ptr[base + 0] = prefix; prefix += v0;
  if (base + 1 < N) row_ptr[base + 1] = prefix; prefix += v1;
  if (base + 2 < N) row_ptr[base + 2] = prefix; prefix += v2;
  if (base + 3 < N) row_ptr[base + 3] = prefix;
  if (blockIdx.x == 0 && t == 0) row_ptr[N] = E;
}

__global__ void scatter_k(const int* __restrict__ ei, int E, int* __restrict__ wp,
                          int* __restrict__ srcs) {
  int e = blockIdx.x * 256 + threadIdx.x;
  if (e < E) {
    int s = ei[e], t = ei[E + e];
    int pos = atomicAdd(&wp[t], 1);
    srcs[pos] = s;
  }
}

// ---- tall-skinny GEMM: out(N x 128) = A(N x 128, fp16) @ W(128 x 128)
// MODE 0: embed  -> outF = acc + bias (fp32 h), outH = fp16 of same
// MODE 1: P      -> outH = fp16(acc)
// MODE 2: aggQ   -> outF = (acc + bias) * indeg   (fp32 agg)
template<int MODE>
__global__ __launch_bounds__(256, 2) void gemm_k(
    const _Float16* __restrict__ Ah, const _Float16* __restrict__ Wt,
    const float* __restrict__ bias, const int* __restrict__ row_ptr,
    float* __restrict__ outF, _Float16* __restrict__ outH, int ntiles)
{
  int lane = threadIdx.x & 63;
  int wid = blockIdx.x * 4 + (threadIdx.x >> 6);
  int nw = gridDim.x * 4;
  int sel = lane & 15, kg = lane >> 4;

  h8 bfrag[8][4];
#pragma unroll
  for (int ct = 0; ct < 8; ++ct)
#pragma unroll
    for (int ks = 0; ks < 4; ++ks)
      bfrag[ct][ks] = *(const h8*)(Wt + (ct * 16 + sel) * H + ks * 32 + kg * 8);

  int t = wid;
  h8 afrag[4];
  if (t < ntiles) {
#pragma unroll
    for (int ks = 0; ks < 4; ++ks)
      afrag[ks] = *(const h8*)(Ah + (t * 16 + sel) * H + ks * 32 + kg * 8);
  }
  while (t < ntiles) {
    int tn = t + nw;
    h8 anext[4];
    if (tn < ntiles) {
#pragma unroll
      for (int ks = 0; ks < 4; ++ks)
        anext[ks] = *(const h8*)(Ah + (tn * 16 + sel) * H + ks * 32 + kg * 8);
    }
    f4 acc[8];
#pragma unroll
    for (int ct = 0; ct < 8; ++ct) acc[ct] = (f4){0.f, 0.f, 0.f, 0.f};
#pragma unroll
    for (int ks = 0; ks < 4; ++ks)
#pragma unroll
      for (int ct = 0; ct < 8; ++ct)
        acc[ct] = __builtin_amdgcn_mfma_f32_16x16x32_f16(afrag[ks], bfrag[ct][ks], acc[ct], 0, 0, 0);

    float indeg[4];
    if (MODE == 2) {
#pragma unroll
      for (int j = 0; j < 4; ++j) {
        int r = t * 16 + kg * 4 + j;
        indeg[j] = (float)(row_ptr[r + 1] - row_ptr[r]);
      }
    }
#pragma unroll
    for (int ct = 0; ct < 8; ++ct) {
      int c = ct * 16 + sel;
      float bv = (MODE == 1) ? 0.f : bias[c];
#pragma unroll
      for (int j = 0; j < 4; ++j) {
        int r = t * 16 + kg * 4 + j;
        float v = acc[ct][j];
        if (MODE == 0) { v += bv; outF[r * H + c] = v; outH[r * H + c] = (_Float16)v; }
        else if (MODE == 1) { outH[r * H + c] = (_Float16)v; }
        else { outF[r * H + c] = (v + bv) * indeg[j]; }
      }
    }
#pragma unroll
    for (int ks = 0; ks < 4; ++ks) afrag[ks] = anext[ks];
    t = tn;
  }
}

// ---- per-node gather of P rows + h update: h = relu(h + agg + sum P[src])
__global__ void agg_update(const _Float16* __restrict__ P, const int* __restrict__ row_ptr,
                           const int* __restrict__ srcs, float* __restrict__ h,
                           const float* __restrict__ agg, _Float16* __restrict__ hh, int N)
{
  int node = blockIdx.x * 4 + (threadIdx.x >> 6);
  if (node >= N) return;
  int lane = threadIdx.x & 63;
  const unsigned* Pu = (const unsigned*)P;
  int e = row_ptr[node], end = row_ptr[node + 1];
  float a0 = 0.f, a1 = 0.f;
  for (; e + 4 <= end; e += 4) {
    int s0 = srcs[e], s1 = srcs[e + 1], s2 = srcs[e + 2], s3 = srcs[e + 3];
    unsigned v0 = Pu[s0 * 64 + lane], v1 = Pu[s1 * 64 + lane];
    unsigned v2 = Pu[s2 * 64 + lane], v3 = Pu[s3 * 64 + lane];
    a0 += u2f_lo(v0) + u2f_lo(v1) + u2f_lo(v2) + u2f_lo(v3);
    a1 += u2f_hi(v0) + u2f_hi(v1) + u2f_hi(v2) + u2f_hi(v3);
  }
  for (; e < end; ++e) {
    unsigned v = Pu[srcs[e] * 64 + lane];
    a0 += u2f_lo(v); a1 += u2f_hi(v);
  }
  int idx = node * H + lane * 2;
  float r0 = fmaxf(h[idx]     + agg[idx]     + a0, 0.f);
  float r1 = fmaxf(h[idx + 1] + agg[idx + 1] + a1, 0.f);
  h[idx] = r0; h[idx + 1] = r1;
  union { _Float16 hf[2]; unsigned u; } pk;
  pk.hf[0] = (_Float16)r0; pk.hf[1] = (_Float16)r1;
  ((unsigned*)hh)[node * 64 + lane] = pk.u;
}

// ---- mean pool (batch sorted): per-block segmented accumulate, atomics on segment change
__global__ void pool_k(const float* __restrict__ h, const int* __restrict__ batch,
                       float* __restrict__ gsum, float* __restrict__ gcnt, int N)
{
  int t = threadIdx.x, col = t & 127, half = t >> 7;
  int per = (N + gridDim.x - 1) / gridDim.x;
  int s = blockIdx.x * per;
  int e = s + per; if (e > N) e = N;
  float acc = 0.f; int cnt = 0, cur = -1;
  for (int n = s + half; n < e; n += 2) {
    int b = batch[n];
    if (b != cur) {
      if (cur >= 0) {
        atomicAdd(&gsum[cur * H + col], acc);
        if (col == 0) atomicAdd(&gcnt[cur], (float)cnt);
      }
      acc = 0.f; cnt = 0; cur = b;
    }
    acc += h[n * H + col]; ++cnt;
  }
  if (cur >= 0) {
    atomicAdd(&gsum[cur * H + col], acc);
    if (col == 0) atomicAdd(&gcnt[cur], (float)cnt);
  }
}

__global__ void readout1(const float* __restrict__ gsum, const float* __restrict__ gcnt,
                         const float* __restrict__ W1, const float* __restrict__ b1,
                         float* __restrict__ hidden)
{
  int b = blockIdx.x, j = threadIdx.x;
  __shared__ float g[H];
  if (j < H) g[j] = gsum[b * H + j] / fmaxf(gcnt[b], 1.f);
  __syncthreads();
  float s = b1[j];
  for (int k = 0; k < H; ++k) s += g[k] * W1[k * HH2 + j];
  hidden[b * HH2 + j] = fmaxf(s, 0.f);
}

__global__ void readout2(const float* __restrict__ hidden, const float* __restrict__ W2,
                         const float* __restrict__ b2, float* __restrict__ out)
{
  int gid = blockIdx.x * 256 + threadIdx.x;
  int b = gid >> 11, m = gid & 2047;
  __shared__ float hs[HH2];
  hs[threadIdx.x] = hidden[b * HH2 + threadIdx.x];
  __syncthreads();
  float s = b2[m];
  for (int j = 0; j < HH2; ++j) s += hs[j] * W2[j * M_OUT + m];
  out[gid] = 6.283185307179586f / (1.f + expf(-s));
}

extern "C" void kernel_launch(void* const* d_in, const int* in_sizes, int n_in,
                              void* d_out, int out_size, void* d_ws, size_t ws_size,
                              hipStream_t stream) {
  const float* x       = (const float*)d_in[0];
  const int*   ei      = (const int*)d_in[1];
  const int*   batch   = (const int*)d_in[2];
  const float* W_embed = (const float*)d_in[3];
  const float* b_embed = (const float*)d_in[4];
  const float* Wm      = (const float*)d_in[5];
  const float* bm      = (const float*)d_in[6];
  const float* W1      = (const float*)d_in[7];
  const float* b1      = (const float*)d_in[8];
  const float* W2      = (const float*)d_in[9];
  const float* b2      = (const float*)d_in[10];
  float* out = (float*)d_out;

  const int N = in_sizes[0] / H;
  const int E = in_sizes[1] / 2;

  char* p = (char*)d_ws;
  auto carve = [&](size_t bytes) { void* r = (void*)p; p += (bytes + 255) & ~(size_t)255; return r; };
  float*     hbuf    = (float*)carve((size_t)N * H * 4);
  float*     agg     = (float*)carve((size_t)N * H * 4);
  _Float16*  hh      = (_Float16*)carve((size_t)N * H * 2);
  _Float16*  Pbuf    = (_Float16*)carve((size_t)N * H * 2);   // also xb scratch
  int*       cnt     = (int*)carve((size_t)(N + 1) * 4);
  int*       row_ptr = (int*)carve((size_t)(N + 1) * 4);
  int*       wp      = (int*)carve((size_t)N * 4);
  int*       srcs    = (int*)carve((size_t)E * 4);
  int*       bsum    = (int*)carve(128 * 4);
  _Float16*  WtAll   = (_Float16*)carve(7 * 16384 * 2);
  float*     gsum    = (float*)carve(16 * H * 4);
  float*     gcnt    = (float*)carve(16 * 4);
  float*     hidden  = (float*)carve(16 * HH2 * 4);

  hipMemsetAsync(cnt, 0, (size_t)(N + 1) * 4, stream);
  hipMemsetAsync(gsum, 0, 16 * H * 4, stream);
  hipMemsetAsync(gcnt, 0, 16 * 4, stream);

  prep_weights<<<(7 * 16384 + 255) / 256, 256, 0, stream>>>(W_embed, Wm, WtAll);
  cvt_f16<<<(N * H / 4 + 255) / 256, 256, 0, stream>>>(x, Pbuf, N * H);

  count_k<<<(E + 255) / 256, 256, 0, stream>>>(ei, E, cnt);
  int nblk = (N + 1023) / 1024;
  sc1<<<nblk, 256, 0, stream>>>(cnt, bsum, N);
  sc2<<<1, 128, 0, stream>>>(bsum, nblk);
  sc3<<<nblk, 256, 0, stream>>>(cnt, bsum, row_ptr, N, E);
  hipMemcpyAsync(wp, row_ptr, (size_t)N * 4, hipMemcpyDeviceToDevice, stream);
  scatter_k<<<(E + 255) / 256, 256, 0, stream>>>(ei, E, wp, srcs);

  int ntiles = N / 16;
  gemm_k<0><<<512, 256, 0, stream>>>(Pbuf, WtAll, b_embed, nullptr, hbuf, hh, ntiles);
  for (int l = 0; l < 3; ++l) {
    gemm_k<1><<<512, 256, 0, stream>>>(hh, WtAll + (1 + 2 * l) * 16384, nullptr, nullptr, nullptr, Pbuf, ntiles);
    gemm_k<2><<<512, 256, 0, stream>>>(hh, WtAll + (2 + 2 * l) * 16384, bm + l * H, row_ptr, agg, nullptr, ntiles);
    agg_update<<<(N + 3) / 4, 256, 0, stream>>>(Pbuf, row_ptr, srcs, hbuf, agg, hh, N);
  }
  pool_k<<<512, 256, 0, stream>>>(hbuf, batch, gsum, gcnt, N);
  readout1<<<16, HH2, 0, stream>>>(gsum, gcnt, W1, b1, hidden);
  readout2<<<16 * M_OUT / 256, 256, 0, stream>>>(hidden, W2, b2, out);
}

// Round 2
// 494.481 us; speedup vs baseline: 1.3242x; 1.3242x over previous
//
#include <hip/hip_runtime.h>

typedef _Float16 h8 __attribute__((ext_vector_type(8)));
typedef float f4 __attribute__((ext_vector_type(4)));

#define H 128
#define HH2 256
#define M_OUT 2048
#define CB 128           // chunk blocks for histogram/scatter
#define MAXBUCK 1024     // supports N <= 131072

__device__ __forceinline__ float u2f_lo(unsigned v) {
  union { unsigned short s; _Float16 h; } c; c.s = (unsigned short)(v & 0xffffu); return (float)c.h;
}
__device__ __forceinline__ float u2f_hi(unsigned v) {
  union { unsigned short s; _Float16 h; } c; c.s = (unsigned short)(v >> 16); return (float)c.h;
}

// ---- weight prep: transpose + fp16 convert. mat 0 = W_embed, 1+2l = Wtop_l, 2+2l = Wbot_l
__global__ void prep_weights(const float* __restrict__ We, const float* __restrict__ Wm,
                             _Float16* __restrict__ WtAll) {
  int gid = blockIdx.x * 256 + threadIdx.x;
  if (gid >= 7 * 16384) return;
  int m = gid >> 14, rem = gid & 16383, c = rem >> 7, k = rem & 127;
  float v;
  if (m == 0) v = We[k * H + c];
  else {
    int l = (m - 1) >> 1, bot = (m - 1) & 1;
    v = Wm[l * (2 * H * H) + (bot * H + k) * H + c];
  }
  WtAll[m * 16384 + c * H + k] = (_Float16)v;   // row = out-col, contiguous k
}

__global__ void cvt_f16(const float* __restrict__ x, _Float16* __restrict__ xb, int n) {
  int i = (blockIdx.x * 256 + threadIdx.x) * 4;
  if (i >= n) return;
  float4 v = *(const float4*)(x + i);
  union { _Float16 h[4]; uint2 u; } o;
  o.h[0] = (_Float16)v.x; o.h[1] = (_Float16)v.y; o.h[2] = (_Float16)v.z; o.h[3] = (_Float16)v.w;
  *(uint2*)(xb + i) = o.u;
}

// ================= CSR build: atomic-free two-level counting sort =================
// bucket = tgt >> 7  (128 nodes/bucket)

__global__ void hist_k(const int* __restrict__ ei, int E, int chunk,
                       int* __restrict__ hist, int nbuck) {
  __shared__ int bins[MAXBUCK];
  for (int i = threadIdx.x; i < nbuck; i += blockDim.x) bins[i] = 0;
  __syncthreads();
  int s = blockIdx.x * chunk, e = min(s + chunk, E);
  for (int i = s + threadIdx.x; i < e; i += blockDim.x)
    atomicAdd(&bins[ei[E + i] >> 7], 1);
  __syncthreads();
  for (int i = threadIdx.x; i < nbuck; i += blockDim.x)
    hist[blockIdx.x * nbuck + i] = bins[i];
}

// per-bucket exclusive scan over the CB blocks; totals[j] = bucket size
__global__ void scanb_k(int* __restrict__ hist, int* __restrict__ totals, int nbuck) {
  __shared__ int sm[CB];
  int j = blockIdx.x, b = threadIdx.x;
  int v = hist[b * nbuck + j];
  sm[b] = v; __syncthreads();
  for (int off = 1; off < CB; off <<= 1) {
    int add = (b >= off) ? sm[b - off] : 0; __syncthreads();
    sm[b] += add; __syncthreads();
  }
  hist[b * nbuck + j] = sm[b] - v;      // exclusive over blocks
  if (b == CB - 1) totals[j] = sm[b];
}

// exclusive scan of bucket totals -> bucket_base; also row_ptr[N]=E, bbase[nbuck]=E
__global__ void scant_k(const int* __restrict__ totals, int* __restrict__ bbase,
                        int* __restrict__ rowp, int nbuck, int E, int N) {
  __shared__ int sm[MAXBUCK];
  int t = threadIdx.x;
  int v = (t < nbuck) ? totals[t] : 0;
  sm[t] = v; __syncthreads();
  for (int off = 1; off < MAXBUCK; off <<= 1) {
    int add = (t >= off) ? sm[t - off] : 0; __syncthreads();
    sm[t] += add; __syncthreads();
  }
  if (t < nbuck) bbase[t] = sm[t] - v;
  if (t == 0) { bbase[nbuck] = E; rowp[N] = E; }
}

// scatter packed (ltgt<<25)|src into bucket-major order, LDS cursors (no global atomics)
__global__ void scat_k(const int* __restrict__ ei, int E, int chunk,
                       const int* __restrict__ hist, const int* __restrict__ bbase,
                       unsigned* __restrict__ pairs, int nbuck) {
  __shared__ int cur[MAXBUCK];
  for (int i = threadIdx.x; i < nbuck; i += blockDim.x)
    cur[i] = bbase[i] + hist[blockIdx.x * nbuck + i];
  __syncthreads();
  int s = blockIdx.x * chunk, e = min(s + chunk, E);
  for (int i = s + threadIdx.x; i < e; i += blockDim.x) {
    int sv = ei[i], tv = ei[E + i];
    int pos = atomicAdd(&cur[tv >> 7], 1);
    pairs[pos] = ((unsigned)(tv & 127) << 25) | (unsigned)sv;
  }
}

// per-bucket counting sort: 128-bin LDS histogram + scan -> row_ptr, then scatter srcs
__global__ void build_k(const unsigned* __restrict__ pairs, const int* __restrict__ bbase,
                        int* __restrict__ rowp, int* __restrict__ srcs, int N) {
  __shared__ int h128[128];
  __shared__ int pre[128];
  int j = blockIdx.x, t = threadIdx.x;
  int base = bbase[j], end = bbase[j + 1];
  if (t < 128) h128[t] = 0;
  __syncthreads();
  for (int i = base + t; i < end; i += blockDim.x)
    atomicAdd(&h128[pairs[i] >> 25], 1);
  __syncthreads();
  if (t < 128) pre[t] = h128[t];
  __syncthreads();
  for (int off = 1; off < 128; off <<= 1) {
    int add = (t < 128 && t >= off) ? pre[t - off] : 0; __syncthreads();
    if (t < 128) pre[t] += add; __syncthreads();
  }
  if (t < 128) {
    int excl = pre[t] - h128[t];
    int node = j * 128 + t;
    if (node < N) rowp[node] = base + excl;
    h128[t] = excl;                        // reuse as cursor
  }
  __syncthreads();
  for (int i = base + t; i < end; i += blockDim.x) {
    unsigned p = pairs[i];
    int pos = atomicAdd(&h128[p >> 25], 1);
    srcs[base + pos] = (int)(p & 0x1ffffff);
  }
}

// ================= tall-skinny GEMM =================
// out(N x 128) = A(N x 128, fp16) @ W(128 x 128)
// MODE 0: embed  -> outF = acc + bias (fp32 h), outH = fp16 of same
// MODE 1: P      -> outH = fp16(acc)
// MODE 2: aggQ   -> outH = fp16((acc + bias) * indeg)
template<int MODE>
__global__ __launch_bounds__(256, 2) void gemm_k(
    const _Float16* __restrict__ Ah, const _Float16* __restrict__ Wt,
    const float* __restrict__ bias, const int* __restrict__ row_ptr,
    float* __restrict__ outF, _Float16* __restrict__ outH, int ntiles)
{
  int lane = threadIdx.x & 63;
  int wid = blockIdx.x * 4 + (threadIdx.x >> 6);
  int nw = gridDim.x * 4;
  int sel = lane & 15, kg = lane >> 4;

  h8 bfrag[8][4];
#pragma unroll
  for (int ct = 0; ct < 8; ++ct)
#pragma unroll
    for (int ks = 0; ks < 4; ++ks)
      bfrag[ct][ks] = *(const h8*)(Wt + (ct * 16 + sel) * H + ks * 32 + kg * 8);

  int t = wid;
  h8 afrag[4];
  if (t < ntiles) {
#pragma unroll
    for (int ks = 0; ks < 4; ++ks)
      afrag[ks] = *(const h8*)(Ah + (t * 16 + sel) * H + ks * 32 + kg * 8);
  }
  while (t < ntiles) {
    int tn = t + nw;
    h8 anext[4];
    if (tn < ntiles) {
#pragma unroll
      for (int ks = 0; ks < 4; ++ks)
        anext[ks] = *(const h8*)(Ah + (tn * 16 + sel) * H + ks * 32 + kg * 8);
    }
    f4 acc[8];
#pragma unroll
    for (int ct = 0; ct < 8; ++ct) acc[ct] = (f4){0.f, 0.f, 0.f, 0.f};
#pragma unroll
    for (int ks = 0; ks < 4; ++ks)
#pragma unroll
      for (int ct = 0; ct < 8; ++ct)
        acc[ct] = __builtin_amdgcn_mfma_f32_16x16x32_f16(afrag[ks], bfrag[ct][ks], acc[ct], 0, 0, 0);

    float indeg[4];
    if (MODE == 2) {
#pragma unroll
      for (int j = 0; j < 4; ++j) {
        int r = t * 16 + kg * 4 + j;
        indeg[j] = (float)(row_ptr[r + 1] - row_ptr[r]);
      }
    }
#pragma unroll
    for (int ct = 0; ct < 8; ++ct) {
      int c = ct * 16 + sel;
      float bv = (MODE == 1) ? 0.f : bias[c];
#pragma unroll
      for (int j = 0; j < 4; ++j) {
        int r = t * 16 + kg * 4 + j;
        float v = acc[ct][j];
        if (MODE == 0) { v += bv; outF[r * H + c] = v; outH[r * H + c] = (_Float16)v; }
        else if (MODE == 1) { outH[r * H + c] = (_Float16)v; }
        else { outH[r * H + c] = (_Float16)((v + bv) * indeg[j]); }
      }
    }
#pragma unroll
    for (int ks = 0; ks < 4; ++ks) afrag[ks] = anext[ks];
    t = tn;
  }
}

// ---- per-node gather of P rows + h update: h = relu(h + agg + sum P[src])
__global__ void agg_update(const _Float16* __restrict__ P, const int* __restrict__ row_ptr,
                           const int* __restrict__ srcs, float* __restrict__ h,
                           const _Float16* __restrict__ aggH, _Float16* __restrict__ hh, int N)
{
  int node = blockIdx.x * 4 + (threadIdx.x >> 6);
  if (node >= N) return;
  int lane = threadIdx.x & 63;
  const unsigned* Pu = (const unsigned*)P;
  int e = row_ptr[node], end = row_ptr[node + 1];
  float a0 = 0.f, a1 = 0.f;
  for (; e + 4 <= end; e += 4) {
    int s0 = srcs[e], s1 = srcs[e + 1], s2 = srcs[e + 2], s3 = srcs[e + 3];
    unsigned v0 = Pu[s0 * 64 + lane], v1 = Pu[s1 * 64 + lane];
    unsigned v2 = Pu[s2 * 64 + lane], v3 = Pu[s3 * 64 + lane];
    a0 += u2f_lo(v0) + u2f_lo(v1) + u2f_lo(v2) + u2f_lo(v3);
    a1 += u2f_hi(v0) + u2f_hi(v1) + u2f_hi(v2) + u2f_hi(v3);
  }
  for (; e < end; ++e) {
    unsigned v = Pu[srcs[e] * 64 + lane];
    a0 += u2f_lo(v); a1 += u2f_hi(v);
  }
  unsigned av = ((const unsigned*)aggH)[node * 64 + lane];
  int idx = node * H + lane * 2;
  float r0 = fmaxf(h[idx]     + u2f_lo(av) + a0, 0.f);
  float r1 = fmaxf(h[idx + 1] + u2f_hi(av) + a1, 0.f);
  h[idx] = r0; h[idx + 1] = r1;
  union { _Float16 hf[2]; unsigned u; } pk;
  pk.hf[0] = (_Float16)r0; pk.hf[1] = (_Float16)r1;
  ((unsigned*)hh)[node * 64 + lane] = pk.u;
}

// ---- mean pool (batch sorted): per-block segmented accumulate, atomics on segment change
__global__ void pool_k(const float* __restrict__ h, const int* __restrict__ batch,
                       float* __restrict__ gsum, float* __restrict__ gcnt, int N)
{
  int t = threadIdx.x, col = t & 127, half = t >> 7;
  int per = (N + gridDim.x - 1) / gridDim.x;
  int s = blockIdx.x * per;
  int e = s + per; if (e > N) e = N;
  float acc = 0.f; int cnt = 0, cur = -1;
  for (int n = s + half; n < e; n += 2) {
    int b = batch[n];
    if (b != cur) {
      if (cur >= 0) {
        atomicAdd(&gsum[cur * H + col], acc);
        if (col == 0) atomicAdd(&gcnt[cur], (float)cnt);
      }
      acc = 0.f; cnt = 0; cur = b;
    }
    acc += h[n * H + col]; ++cnt;
  }
  if (cur >= 0) {
    atomicAdd(&gsum[cur * H + col], acc);
    if (col == 0) atomicAdd(&gcnt[cur], (float)cnt);
  }
}

__global__ void readout1(const float* __restrict__ gsum, const float* __restrict__ gcnt,
                         const float* __restrict__ W1, const float* __restrict__ b1,
                         float* __restrict__ hidden)
{
  int b = blockIdx.x, j = threadIdx.x;
  __shared__ float g[H];
  if (j < H) g[j] = gsum[b * H + j] / fmaxf(gcnt[b], 1.f);
  __syncthreads();
  float s = b1[j];
  for (int k = 0; k < H; ++k) s += g[k] * W1[k * HH2 + j];
  hidden[b * HH2 + j] = fmaxf(s, 0.f);
}

__global__ void readout2(const float* __restrict__ hidden, const float* __restrict__ W2,
                         const float* __restrict__ b2, float* __restrict__ out)
{
  int gid = blockIdx.x * 256 + threadIdx.x;
  int b = gid >> 11, m = gid & 2047;
  __shared__ float hs[HH2];
  hs[threadIdx.x] = hidden[b * HH2 + threadIdx.x];
  __syncthreads();
  float s = b2[m];
  for (int j = 0; j < HH2; ++j) s += hs[j] * W2[j * M_OUT + m];
  out[gid] = 6.283185307179586f / (1.f + expf(-s));
}

extern "C" void kernel_launch(void* const* d_in, const int* in_sizes, int n_in,
                              void* d_out, int out_size, void* d_ws, size_t ws_size,
                              hipStream_t stream) {
  const float* x       = (const float*)d_in[0];
  const int*   ei      = (const int*)d_in[1];
  const int*   batch   = (const int*)d_in[2];
  const float* W_embed = (const float*)d_in[3];
  const float* b_embed = (const float*)d_in[4];
  const float* Wm      = (const float*)d_in[5];
  const float* bm      = (const float*)d_in[6];
  const float* W1      = (const float*)d_in[7];
  const float* b1      = (const float*)d_in[8];
  const float* W2      = (const float*)d_in[9];
  const float* b2      = (const float*)d_in[10];
  float* out = (float*)d_out;

  const int N = in_sizes[0] / H;
  const int E = in_sizes[1] / 2;
  const int nbuck = (N + 127) >> 7;
  const int chunk = (E + CB - 1) / CB;

  char* p = (char*)d_ws;
  auto carve = [&](size_t bytes) { void* r = (void*)p; p += (bytes + 255) & ~(size_t)255; return r; };
  float*     hbuf    = (float*)carve((size_t)N * H * 4);
  _Float16*  aggH    = (_Float16*)carve((size_t)N * H * 2);
  _Float16*  hh      = (_Float16*)carve((size_t)N * H * 2);
  _Float16*  Pbuf    = (_Float16*)carve((size_t)N * H * 2);   // also xb scratch
  int*       row_ptr = (int*)carve((size_t)(N + 1) * 4);
  int*       srcs    = (int*)carve((size_t)E * 4);
  unsigned*  pairs   = (unsigned*)carve((size_t)E * 4);
  int*       hist    = (int*)carve((size_t)CB * MAXBUCK * 4);
  int*       totals  = (int*)carve((size_t)(MAXBUCK + 1) * 4);
  int*       bbase   = (int*)carve((size_t)(MAXBUCK + 1) * 4);
  _Float16*  WtAll   = (_Float16*)carve(7 * 16384 * 2);
  float*     gsum    = (float*)carve(16 * H * 4);
  float*     gcnt    = (float*)carve(16 * 4);
  float*     hidden  = (float*)carve(16 * HH2 * 4);

  hipMemsetAsync(gsum, 0, 16 * H * 4, stream);
  hipMemsetAsync(gcnt, 0, 16 * 4, stream);

  prep_weights<<<(7 * 16384 + 255) / 256, 256, 0, stream>>>(W_embed, Wm, WtAll);
  cvt_f16<<<(N * H / 4 + 255) / 256, 256, 0, stream>>>(x, Pbuf, N * H);

  // CSR build (atomic-free)
  hist_k<<<CB, 1024, 0, stream>>>(ei, E, chunk, hist, nbuck);
  scanb_k<<<nbuck, CB, 0, stream>>>(hist, totals, nbuck);
  scant_k<<<1, MAXBUCK, 0, stream>>>(totals, bbase, row_ptr, nbuck, E, N);
  scat_k<<<CB, 1024, 0, stream>>>(ei, E, chunk, hist, bbase, pairs, nbuck);
  build_k<<<nbuck, 256, 0, stream>>>(pairs, bbase, row_ptr, srcs, N);

  int ntiles = N / 16;
  gemm_k<0><<<512, 256, 0, stream>>>(Pbuf, WtAll, b_embed, nullptr, hbuf, hh, ntiles);
  for (int l = 0; l < 3; ++l) {
    gemm_k<1><<<512, 256, 0, stream>>>(hh, WtAll + (1 + 2 * l) * 16384, nullptr, nullptr, nullptr, Pbuf, ntiles);
    gemm_k<2><<<512, 256, 0, stream>>>(hh, WtAll + (2 + 2 * l) * 16384, bm + l * H, row_ptr, nullptr, aggH, ntiles);
    agg_update<<<(N + 3) / 4, 256, 0, stream>>>(Pbuf, row_ptr, srcs, hbuf, aggH, hh, N);
  }
  pool_k<<<512, 256, 0, stream>>>(hbuf, batch, gsum, gcnt, N);
  readout1<<<16, HH2, 0, stream>>>(gsum, gcnt, W1, b1, hidden);
  readout2<<<16 * M_OUT / 256, 256, 0, stream>>>(hidden, W2, b2, out);
}

// Round 4
// 438.565 us; speedup vs baseline: 1.4930x; 1.1275x over previous
//
#include <hip/hip_runtime.h>

typedef _Float16 h8 __attribute__((ext_vector_type(8)));
typedef float f4 __attribute__((ext_vector_type(4)));

#define H 128
#define HH2 256
#define M_OUT 2048
#define CB 128           // chunk blocks for histogram/scatter
#define MAXBUCK 1024     // supports N <= 131072

__device__ __forceinline__ float u2f_lo(unsigned v) {
  union { unsigned short s; _Float16 h; } c; c.s = (unsigned short)(v & 0xffffu); return (float)c.h;
}
__device__ __forceinline__ float u2f_hi(unsigned v) {
  union { unsigned short s; _Float16 h; } c; c.s = (unsigned short)(v >> 16); return (float)c.h;
}

// ---- weight prep: transpose + fp16 convert. mat 0 = W_embed, 1+2l = Wtop_l, 2+2l = Wbot_l
__global__ void prep_weights(const float* __restrict__ We, const float* __restrict__ Wm,
                             _Float16* __restrict__ WtAll) {
  int gid = blockIdx.x * 256 + threadIdx.x;
  if (gid >= 7 * 16384) return;
  int m = gid >> 14, rem = gid & 16383, c = rem >> 7, k = rem & 127;
  float v;
  if (m == 0) v = We[k * H + c];
  else {
    int l = (m - 1) >> 1, bot = (m - 1) & 1;
    v = Wm[l * (2 * H * H) + (bot * H + k) * H + c];
  }
  WtAll[m * 16384 + c * H + k] = (_Float16)v;   // row = out-col, contiguous k
}

__global__ void cvt_f16(const float* __restrict__ x, _Float16* __restrict__ xb, int n) {
  int i = (blockIdx.x * 256 + threadIdx.x) * 4;
  if (i >= n) return;
  float4 v = *(const float4*)(x + i);
  union { _Float16 h[4]; uint2 u; } o;
  o.h[0] = (_Float16)v.x; o.h[1] = (_Float16)v.y; o.h[2] = (_Float16)v.z; o.h[3] = (_Float16)v.w;
  *(uint2*)(xb + i) = o.u;
}

// ================= CSR build: atomic-free two-level counting sort =================
// bucket = tgt >> 7  (128 nodes/bucket)

__global__ void hist_k(const int* __restrict__ ei, int E, int chunk,
                       int* __restrict__ hist, int nbuck) {
  __shared__ int bins[MAXBUCK];
  for (int i = threadIdx.x; i < nbuck; i += blockDim.x) bins[i] = 0;
  __syncthreads();
  int s = blockIdx.x * chunk, e = min(s + chunk, E);
  for (int i = s + threadIdx.x; i < e; i += blockDim.x)
    atomicAdd(&bins[ei[E + i] >> 7], 1);
  __syncthreads();
  for (int i = threadIdx.x; i < nbuck; i += blockDim.x)
    hist[blockIdx.x * nbuck + i] = bins[i];
}

// per-bucket exclusive scan over the CB blocks; totals[j] = bucket size
__global__ void scanb_k(int* __restrict__ hist, int* __restrict__ totals, int nbuck) {
  __shared__ int sm[CB];
  int j = blockIdx.x, b = threadIdx.x;
  int v = hist[b * nbuck + j];
  sm[b] = v; __syncthreads();
  for (int off = 1; off < CB; off <<= 1) {
    int add = (b >= off) ? sm[b - off] : 0; __syncthreads();
    sm[b] += add; __syncthreads();
  }
  hist[b * nbuck + j] = sm[b] - v;      // exclusive over blocks
  if (b == CB - 1) totals[j] = sm[b];
}

// exclusive scan of bucket totals -> bucket_base; also row_ptr[N]=E, bbase[nbuck]=E
__global__ void scant_k(const int* __restrict__ totals, int* __restrict__ bbase,
                        int* __restrict__ rowp, int nbuck, int E, int N) {
  __shared__ int sm[MAXBUCK];
  int t = threadIdx.x;
  int v = (t < nbuck) ? totals[t] : 0;
  sm[t] = v; __syncthreads();
  for (int off = 1; off < MAXBUCK; off <<= 1) {
    int add = (t >= off) ? sm[t - off] : 0; __syncthreads();
    sm[t] += add; __syncthreads();
  }
  if (t < nbuck) bbase[t] = sm[t] - v;
  if (t == 0) { bbase[nbuck] = E; rowp[N] = E; }
}

// scatter packed (ltgt<<25)|src into bucket-major order, LDS cursors (no global atomics)
__global__ void scat_k(const int* __restrict__ ei, int E, int chunk,
                       const int* __restrict__ hist, const int* __restrict__ bbase,
                       unsigned* __restrict__ pairs, int nbuck) {
  __shared__ int cur[MAXBUCK];
  for (int i = threadIdx.x; i < nbuck; i += blockDim.x)
    cur[i] = bbase[i] + hist[blockIdx.x * nbuck + i];
  __syncthreads();
  int s = blockIdx.x * chunk, e = min(s + chunk, E);
  for (int i = s + threadIdx.x; i < e; i += blockDim.x) {
    int sv = ei[i], tv = ei[E + i];
    int pos = atomicAdd(&cur[tv >> 7], 1);
    pairs[pos] = ((unsigned)(tv & 127) << 25) | (unsigned)sv;
  }
}

// per-bucket counting sort: 128-bin LDS histogram + scan -> row_ptr, then scatter srcs
__global__ void build_k(const unsigned* __restrict__ pairs, const int* __restrict__ bbase,
                        int* __restrict__ rowp, int* __restrict__ srcs, int N) {
  __shared__ int h128[128];
  __shared__ int pre[128];
  int j = blockIdx.x, t = threadIdx.x;
  int base = bbase[j], end = bbase[j + 1];
  if (t < 128) h128[t] = 0;
  __syncthreads();
  for (int i = base + t; i < end; i += blockDim.x)
    atomicAdd(&h128[pairs[i] >> 25], 1);
  __syncthreads();
  if (t < 128) pre[t] = h128[t];
  __syncthreads();
  for (int off = 1; off < 128; off <<= 1) {
    int add = (t < 128 && t >= off) ? pre[t - off] : 0; __syncthreads();
    if (t < 128) pre[t] += add; __syncthreads();
  }
  if (t < 128) {
    int excl = pre[t] - h128[t];
    int node = j * 128 + t;
    if (node < N) rowp[node] = base + excl;
    h128[t] = excl;                        // reuse as cursor
  }
  __syncthreads();
  for (int i = base + t; i < end; i += blockDim.x) {
    unsigned p = pairs[i];
    int pos = atomicAdd(&h128[p >> 25], 1);
    srcs[base + pos] = (int)(p & 0x1ffffff);
  }
}

// ================= tall-skinny GEMM =================
// outH(N x 128) = fp16( A(N x 128, fp16) @ W(128 x 128) [+bias] [*indeg] )
// MODE 0: embed -> acc + bias ; MODE 1: P -> acc ; MODE 2: aggQ -> (acc+bias)*indeg
template<int MODE>
__global__ __launch_bounds__(256, 2) void gemm_k(
    const _Float16* __restrict__ Ah, const _Float16* __restrict__ Wt,
    const float* __restrict__ bias, const int* __restrict__ row_ptr,
    _Float16* __restrict__ outH, int ntiles)
{
  int lane = threadIdx.x & 63;
  int wid = blockIdx.x * 4 + (threadIdx.x >> 6);
  int nw = gridDim.x * 4;
  int sel = lane & 15, kg = lane >> 4;

  h8 bfrag[8][4];
#pragma unroll
  for (int ct = 0; ct < 8; ++ct)
#pragma unroll
    for (int ks = 0; ks < 4; ++ks)
      bfrag[ct][ks] = *(const h8*)(Wt + (ct * 16 + sel) * H + ks * 32 + kg * 8);

  int t = wid;
  h8 afrag[4];
  if (t < ntiles) {
#pragma unroll
    for (int ks = 0; ks < 4; ++ks)
      afrag[ks] = *(const h8*)(Ah + (t * 16 + sel) * H + ks * 32 + kg * 8);
  }
  while (t < ntiles) {
    int tn = t + nw;
    h8 anext[4];
    if (tn < ntiles) {
#pragma unroll
      for (int ks = 0; ks < 4; ++ks)
        anext[ks] = *(const h8*)(Ah + (tn * 16 + sel) * H + ks * 32 + kg * 8);
    }
    f4 acc[8];
#pragma unroll
    for (int ct = 0; ct < 8; ++ct) acc[ct] = (f4){0.f, 0.f, 0.f, 0.f};
#pragma unroll
    for (int ks = 0; ks < 4; ++ks)
#pragma unroll
      for (int ct = 0; ct < 8; ++ct)
        acc[ct] = __builtin_amdgcn_mfma_f32_16x16x32_f16(afrag[ks], bfrag[ct][ks], acc[ct], 0, 0, 0);

    float indeg[4];
    if (MODE == 2) {
#pragma unroll
      for (int j = 0; j < 4; ++j) {
        int r = t * 16 + kg * 4 + j;
        indeg[j] = (float)(row_ptr[r + 1] - row_ptr[r]);
      }
    }
#pragma unroll
    for (int ct = 0; ct < 8; ++ct) {
      int c = ct * 16 + sel;
      float bv = (MODE == 1) ? 0.f : bias[c];
#pragma unroll
      for (int j = 0; j < 4; ++j) {
        int r = t * 16 + kg * 4 + j;
        float v = acc[ct][j];
        if (MODE == 0) outH[r * H + c] = (_Float16)(v + bv);
        else if (MODE == 1) outH[r * H + c] = (_Float16)v;
        else outH[r * H + c] = (_Float16)((v + bv) * indeg[j]);
      }
    }
#pragma unroll
    for (int ks = 0; ks < 4; ++ks) afrag[ks] = anext[ks];
    t = tn;
  }
}

// ---- per-node gather of P rows + h update: hh = relu(hh + aggH + sum P[src])
// Each half-wave (32 lanes x uint2 = 256B) reads one P row -> 2 edges per step.
// srcs preloaded 64-at-a-time, broadcast via shfl. ALL shfls execute at
// wave-uniform control points (loop bounds depend only on uniform cnt) —
// shfl from an inactive lane is undefined on CDNA.
__global__ __launch_bounds__(256) void agg_update(
    const _Float16* __restrict__ P, const int* __restrict__ rowp,
    const int* __restrict__ srcs, const _Float16* __restrict__ aggH,
    _Float16* hh, int N)
{
  int node = blockIdx.x * 4 + (threadIdx.x >> 6);
  if (node >= N) return;
  int lane = threadIdx.x & 63;
  int half = lane >> 5, li = lane & 31;
  const uint2* P2 = (const uint2*)P;
  float a0 = 0.f, a1 = 0.f, a2 = 0.f, a3 = 0.f;
  int e = rowp[node], end = rowp[node + 1];
  while (e < end) {
    int cnt = min(end - e, 64);          // wave-uniform
    int myS = (lane < cnt) ? srcs[e + lane] : 0;
    int j = 0;
    // main: 8 edges/iter, all shfl indices j+half..j+6+half <= cnt-1 (valid, all lanes active)
    for (; j + 8 <= cnt; j += 8) {
      int s0 = __shfl(myS, j + half);
      int s1 = __shfl(myS, j + 2 + half);
      int s2 = __shfl(myS, j + 4 + half);
      int s3 = __shfl(myS, j + 6 + half);
      uint2 v0 = P2[s0 * 32 + li], v1 = P2[s1 * 32 + li];
      uint2 v2 = P2[s2 * 32 + li], v3 = P2[s3 * 32 + li];
      a0 += u2f_lo(v0.x) + u2f_lo(v1.x) + u2f_lo(v2.x) + u2f_lo(v3.x);
      a1 += u2f_hi(v0.x) + u2f_hi(v1.x) + u2f_hi(v2.x) + u2f_hi(v3.x);
      a2 += u2f_lo(v0.y) + u2f_lo(v1.y) + u2f_lo(v2.y) + u2f_lo(v3.y);
      a3 += u2f_hi(v0.y) + u2f_hi(v1.y) + u2f_hi(v2.y) + u2f_hi(v3.y);
    }
    // tail: uniform bound; shfl outside the guard, only load+add predicated
    for (; j < cnt; j += 2) {
      int jj = j + half;
      int s = __shfl(myS, (jj < cnt) ? jj : (cnt - 1));
      if (jj < cnt) {
        uint2 v = P2[s * 32 + li];
        a0 += u2f_lo(v.x); a1 += u2f_hi(v.x);
        a2 += u2f_lo(v.y); a3 += u2f_hi(v.y);
      }
    }
    e += cnt;
  }
  a0 += __shfl_xor(a0, 32); a1 += __shfl_xor(a1, 32);
  a2 += __shfl_xor(a2, 32); a3 += __shfl_xor(a3, 32);
  if (half == 0) {
    int idx = node * 32 + li;
    uint2 hv = ((const uint2*)hh)[idx];
    uint2 av = ((const uint2*)aggH)[idx];
    float r0 = fmaxf(u2f_lo(hv.x) + u2f_lo(av.x) + a0, 0.f);
    float r1 = fmaxf(u2f_hi(hv.x) + u2f_hi(av.x) + a1, 0.f);
    float r2 = fmaxf(u2f_lo(hv.y) + u2f_lo(av.y) + a2, 0.f);
    float r3 = fmaxf(u2f_hi(hv.y) + u2f_hi(av.y) + a3, 0.f);
    union { _Float16 h[4]; uint2 u; } pk;
    pk.h[0] = (_Float16)r0; pk.h[1] = (_Float16)r1;
    pk.h[2] = (_Float16)r2; pk.h[3] = (_Float16)r3;
    ((uint2*)hh)[idx] = pk.u;
  }
}

// ---- mean pool (batch sorted): fp16 input, 4 row-substreams x 64 u32-cols
__global__ void pool_k(const _Float16* __restrict__ hh, const int* __restrict__ batch,
                       float* __restrict__ gsum, float* __restrict__ gcnt, int N)
{
  int t = threadIdx.x, c2 = t & 63, sub = t >> 6;
  int per = (N + gridDim.x - 1) / gridDim.x;
  int s = blockIdx.x * per;
  int e = s + per; if (e > N) e = N;
  const unsigned* hu = (const unsigned*)hh;
  float a0 = 0.f, a1 = 0.f; int cnt = 0, cur = -1;
  for (int n = s + sub; n < e; n += 4) {
    int b = batch[n];
    if (b != cur) {
      if (cur >= 0) {
        atomicAdd(&gsum[cur * H + c2 * 2], a0);
        atomicAdd(&gsum[cur * H + c2 * 2 + 1], a1);
        if (c2 == 0) atomicAdd(&gcnt[cur], (float)cnt);
      }
      a0 = 0.f; a1 = 0.f; cnt = 0; cur = b;
    }
    unsigned v = hu[n * 64 + c2];
    a0 += u2f_lo(v); a1 += u2f_hi(v); ++cnt;
  }
  if (cur >= 0) {
    atomicAdd(&gsum[cur * H + c2 * 2], a0);
    atomicAdd(&gsum[cur * H + c2 * 2 + 1], a1);
    if (c2 == 0) atomicAdd(&gcnt[cur], (float)cnt);
  }
}

__global__ void readout1(const float* __restrict__ gsum, const float* __restrict__ gcnt,
                         const float* __restrict__ W1, const float* __restrict__ b1,
                         float* __restrict__ hidden)
{
  int b = blockIdx.x, j = threadIdx.x;
  __shared__ float g[H];
  if (j < H) g[j] = gsum[b * H + j] / fmaxf(gcnt[b], 1.f);
  __syncthreads();
  float s = b1[j];
  for (int k = 0; k < H; ++k) s += g[k] * W1[k * HH2 + j];
  hidden[b * HH2 + j] = fmaxf(s, 0.f);
}

__global__ void readout2(const float* __restrict__ hidden, const float* __restrict__ W2,
                         const float* __restrict__ b2, float* __restrict__ out)
{
  int gid = blockIdx.x * 256 + threadIdx.x;
  int b = gid >> 11, m = gid & 2047;
  __shared__ float hs[HH2];
  hs[threadIdx.x] = hidden[b * HH2 + threadIdx.x];
  __syncthreads();
  float s = b2[m];
  for (int j = 0; j < HH2; ++j) s += hs[j] * W2[j * M_OUT + m];
  out[gid] = 6.283185307179586f / (1.f + expf(-s));
}

extern "C" void kernel_launch(void* const* d_in, const int* in_sizes, int n_in,
                              void* d_out, int out_size, void* d_ws, size_t ws_size,
                              hipStream_t stream) {
  const float* x       = (const float*)d_in[0];
  const int*   ei      = (const int*)d_in[1];
  const int*   batch   = (const int*)d_in[2];
  const float* W_embed = (const float*)d_in[3];
  const float* b_embed = (const float*)d_in[4];
  const float* Wm      = (const float*)d_in[5];
  const float* bm      = (const float*)d_in[6];
  const float* W1      = (const float*)d_in[7];
  const float* b1      = (const float*)d_in[8];
  const float* W2      = (const float*)d_in[9];
  const float* b2      = (const float*)d_in[10];
  float* out = (float*)d_out;

  const int N = in_sizes[0] / H;
  const int E = in_sizes[1] / 2;
  const int nbuck = (N + 127) >> 7;
  const int chunk = (E + CB - 1) / CB;

  char* p = (char*)d_ws;
  auto carve = [&](size_t bytes) { void* r = (void*)p; p += (bytes + 255) & ~(size_t)255; return r; };
  _Float16*  hh      = (_Float16*)carve((size_t)N * H * 2);
  _Float16*  aggH    = (_Float16*)carve((size_t)N * H * 2);
  _Float16*  Pbuf    = (_Float16*)carve((size_t)N * H * 2);   // also xb scratch
  int*       row_ptr = (int*)carve((size_t)(N + 1) * 4);
  int*       srcs    = (int*)carve((size_t)E * 4);
  unsigned*  pairs   = (unsigned*)carve((size_t)E * 4);
  int*       hist    = (int*)carve((size_t)CB * MAXBUCK * 4);
  int*       totals  = (int*)carve((size_t)(MAXBUCK + 1) * 4);
  int*       bbase   = (int*)carve((size_t)(MAXBUCK + 1) * 4);
  _Float16*  WtAll   = (_Float16*)carve(7 * 16384 * 2);
  float*     gsum    = (float*)carve(16 * H * 4);
  float*     gcnt    = (float*)carve(16 * 4);
  float*     hidden  = (float*)carve(16 * HH2 * 4);

  hipMemsetAsync(gsum, 0, 16 * H * 4, stream);
  hipMemsetAsync(gcnt, 0, 16 * 4, stream);

  prep_weights<<<(7 * 16384 + 255) / 256, 256, 0, stream>>>(W_embed, Wm, WtAll);
  cvt_f16<<<(N * H / 4 + 255) / 256, 256, 0, stream>>>(x, Pbuf, N * H);

  // CSR build (atomic-free at global scope)
  hist_k<<<CB, 1024, 0, stream>>>(ei, E, chunk, hist, nbuck);
  scanb_k<<<nbuck, CB, 0, stream>>>(hist, totals, nbuck);
  scant_k<<<1, MAXBUCK, 0, stream>>>(totals, bbase, row_ptr, nbuck, E, N);
  scat_k<<<CB, 1024, 0, stream>>>(ei, E, chunk, hist, bbase, pairs, nbuck);
  build_k<<<nbuck, 256, 0, stream>>>(pairs, bbase, row_ptr, srcs, N);

  int ntiles = N / 16;
  gemm_k<0><<<512, 256, 0, stream>>>(Pbuf, WtAll, b_embed, nullptr, hh, ntiles);
  for (int l = 0; l < 3; ++l) {
    gemm_k<1><<<512, 256, 0, stream>>>(hh, WtAll + (1 + 2 * l) * 16384, nullptr, nullptr, Pbuf, ntiles);
    gemm_k<2><<<512, 256, 0, stream>>>(hh, WtAll + (2 + 2 * l) * 16384, bm + l * H, row_ptr, aggH, ntiles);
    agg_update<<<(N + 3) / 4, 256, 0, stream>>>(Pbuf, row_ptr, srcs, aggH, hh, N);
  }
  pool_k<<<512, 256, 0, stream>>>(hh, batch, gsum, gcnt, N);
  readout1<<<16, HH2, 0, stream>>>(gsum, gcnt, W1, b1, hidden);
  readout2<<<16 * M_OUT / 256, 256, 0, stream>>>(hidden, W2, b2, out);
}

// Round 5
// 425.464 us; speedup vs baseline: 1.5390x; 1.0308x over previous
//
#include <hip/hip_runtime.h>

typedef _Float16 h8 __attribute__((ext_vector_type(8)));
typedef _Float16 h2 __attribute__((ext_vector_type(2)));
typedef float f4 __attribute__((ext_vector_type(4)));

#define H 128
#define HH2 256
#define M_OUT 2048
#define CB 128           // chunk blocks for histogram/scatter
#define MAXBUCK 1024     // supports N <= 131072

__device__ __forceinline__ float u2f_lo(unsigned v) {
  union { unsigned short s; _Float16 h; } c; c.s = (unsigned short)(v & 0xffffu); return (float)c.h;
}
__device__ __forceinline__ float u2f_hi(unsigned v) {
  union { unsigned short s; _Float16 h; } c; c.s = (unsigned short)(v >> 16); return (float)c.h;
}
__device__ __forceinline__ h2 as_h2(unsigned v) {
  union { unsigned u; h2 h; } c; c.u = v; return c.h;
}

// ---- weight prep: transpose + fp16 convert. mat 0 = W_embed, 1+2l = Wtop_l, 2+2l = Wbot_l
__global__ void prep_weights(const float* __restrict__ We, const float* __restrict__ Wm,
                             _Float16* __restrict__ WtAll) {
  int gid = blockIdx.x * 256 + threadIdx.x;
  if (gid >= 7 * 16384) return;
  int m = gid >> 14, rem = gid & 16383, c = rem >> 7, k = rem & 127;
  float v;
  if (m == 0) v = We[k * H + c];
  else {
    int l = (m - 1) >> 1, bot = (m - 1) & 1;
    v = Wm[l * (2 * H * H) + (bot * H + k) * H + c];
  }
  WtAll[m * 16384 + c * H + k] = (_Float16)v;   // row = out-col, contiguous k
}

// ================= CSR build: atomic-free two-level counting sort =================
// bucket = tgt >> 7  (128 nodes/bucket)

__global__ void hist_k(const int* __restrict__ ei, int E, int chunk,
                       int* __restrict__ hist, int nbuck) {
  __shared__ int bins[MAXBUCK];
  for (int i = threadIdx.x; i < nbuck; i += blockDim.x) bins[i] = 0;
  __syncthreads();
  int s = blockIdx.x * chunk, e = min(s + chunk, E);
  for (int i = s + threadIdx.x; i < e; i += blockDim.x)
    atomicAdd(&bins[ei[E + i] >> 7], 1);
  __syncthreads();
  for (int i = threadIdx.x; i < nbuck; i += blockDim.x)
    hist[blockIdx.x * nbuck + i] = bins[i];
}

// per-bucket exclusive scan over the CB blocks; totals[j] = bucket size
__global__ void scanb_k(int* __restrict__ hist, int* __restrict__ totals, int nbuck) {
  __shared__ int sm[CB];
  int j = blockIdx.x, b = threadIdx.x;
  int v = hist[b * nbuck + j];
  sm[b] = v; __syncthreads();
  for (int off = 1; off < CB; off <<= 1) {
    int add = (b >= off) ? sm[b - off] : 0; __syncthreads();
    sm[b] += add; __syncthreads();
  }
  hist[b * nbuck + j] = sm[b] - v;      // exclusive over blocks
  if (b == CB - 1) totals[j] = sm[b];
}

// exclusive scan of bucket totals -> bucket_base; also row_ptr[N]=E, bbase[nbuck]=E
__global__ void scant_k(const int* __restrict__ totals, int* __restrict__ bbase,
                        int* __restrict__ rowp, int nbuck, int E, int N) {
  __shared__ int sm[MAXBUCK];
  int t = threadIdx.x;
  int v = (t < nbuck) ? totals[t] : 0;
  sm[t] = v; __syncthreads();
  for (int off = 1; off < MAXBUCK; off <<= 1) {
    int add = (t >= off) ? sm[t - off] : 0; __syncthreads();
    sm[t] += add; __syncthreads();
  }
  if (t < nbuck) bbase[t] = sm[t] - v;
  if (t == 0) { bbase[nbuck] = E; rowp[N] = E; }
}

// scatter packed (ltgt<<25)|src into bucket-major order, LDS cursors (no global atomics)
__global__ void scat_k(const int* __restrict__ ei, int E, int chunk,
                       const int* __restrict__ hist, const int* __restrict__ bbase,
                       unsigned* __restrict__ pairs, int nbuck) {
  __shared__ int cur[MAXBUCK];
  for (int i = threadIdx.x; i < nbuck; i += blockDim.x)
    cur[i] = bbase[i] + hist[blockIdx.x * nbuck + i];
  __syncthreads();
  int s = blockIdx.x * chunk, e = min(s + chunk, E);
  for (int i = s + threadIdx.x; i < e; i += blockDim.x) {
    int sv = ei[i], tv = ei[E + i];
    int pos = atomicAdd(&cur[tv >> 7], 1);
    pairs[pos] = ((unsigned)(tv & 127) << 25) | (unsigned)sv;
  }
}

// per-bucket counting sort: 128-bin LDS histogram + scan -> row_ptr, then scatter srcs
__global__ void build_k(const unsigned* __restrict__ pairs, const int* __restrict__ bbase,
                        int* __restrict__ rowp, int* __restrict__ srcs, int N) {
  __shared__ int h128[128];
  __shared__ int pre[128];
  int j = blockIdx.x, t = threadIdx.x;
  int base = bbase[j], end = bbase[j + 1];
  if (t < 128) h128[t] = 0;
  __syncthreads();
  for (int i = base + t; i < end; i += blockDim.x)
    atomicAdd(&h128[pairs[i] >> 25], 1);
  __syncthreads();
  if (t < 128) pre[t] = h128[t];
  __syncthreads();
  for (int off = 1; off < 128; off <<= 1) {
    int add = (t < 128 && t >= off) ? pre[t - off] : 0; __syncthreads();
    if (t < 128) pre[t] += add; __syncthreads();
  }
  if (t < 128) {
    int excl = pre[t] - h128[t];
    int node = j * 128 + t;
    if (node < N) rowp[node] = base + excl;
    h128[t] = excl;                        // reuse as cursor
  }
  __syncthreads();
  for (int i = base + t; i < end; i += blockDim.x) {
    unsigned p = pairs[i];
    int pos = atomicAdd(&h128[p >> 25], 1);
    srcs[base + pos] = (int)(p & 0x1ffffff);
  }
}

// ================= tall-skinny GEMM =================
// outH(N x 128) = fp16( A(N x 128) @ W(128 x 128) [+bias] [*indeg] )
// MODE 0: embed (A = fp32 x, converted in-register) -> acc + bias
// MODE 1: P    -> acc
// MODE 2: aggQ -> (acc+bias)*indeg
template<int MODE>
__global__ __launch_bounds__(256, 2) void gemm_k(
    const _Float16* __restrict__ Ah, const float* __restrict__ Af,
    const _Float16* __restrict__ Wt,
    const float* __restrict__ bias, const int* __restrict__ row_ptr,
    _Float16* __restrict__ outH, int ntiles)
{
  int lane = threadIdx.x & 63;
  int wid = blockIdx.x * 4 + (threadIdx.x >> 6);
  int nw = gridDim.x * 4;
  int sel = lane & 15, kg = lane >> 4;

  h8 bfrag[8][4];
#pragma unroll
  for (int ct = 0; ct < 8; ++ct)
#pragma unroll
    for (int ks = 0; ks < 4; ++ks)
      bfrag[ct][ks] = *(const h8*)(Wt + (ct * 16 + sel) * H + ks * 32 + kg * 8);

  auto load_a = [&](int row, int ks) -> h8 {
    if (MODE == 0) {
      const float* b = Af + row * H + ks * 32 + kg * 8;
      f4 a0 = *(const f4*)b, a1 = *(const f4*)(b + 4);
      h8 r;
      r[0] = (_Float16)a0.x; r[1] = (_Float16)a0.y; r[2] = (_Float16)a0.z; r[3] = (_Float16)a0.w;
      r[4] = (_Float16)a1.x; r[5] = (_Float16)a1.y; r[6] = (_Float16)a1.z; r[7] = (_Float16)a1.w;
      return r;
    } else {
      return *(const h8*)(Ah + row * H + ks * 32 + kg * 8);
    }
  };

  int t = wid;
  h8 afrag[4];
  if (t < ntiles) {
#pragma unroll
    for (int ks = 0; ks < 4; ++ks) afrag[ks] = load_a(t * 16 + sel, ks);
  }
  while (t < ntiles) {
    int tn = t + nw;
    h8 anext[4];
    if (tn < ntiles) {
#pragma unroll
      for (int ks = 0; ks < 4; ++ks) anext[ks] = load_a(tn * 16 + sel, ks);
    }
    f4 acc[8];
#pragma unroll
    for (int ct = 0; ct < 8; ++ct) acc[ct] = (f4){0.f, 0.f, 0.f, 0.f};
#pragma unroll
    for (int ks = 0; ks < 4; ++ks)
#pragma unroll
      for (int ct = 0; ct < 8; ++ct)
        acc[ct] = __builtin_amdgcn_mfma_f32_16x16x32_f16(afrag[ks], bfrag[ct][ks], acc[ct], 0, 0, 0);

    float indeg[4];
    if (MODE == 2) {
#pragma unroll
      for (int j = 0; j < 4; ++j) {
        int r = t * 16 + kg * 4 + j;
        indeg[j] = (float)(row_ptr[r + 1] - row_ptr[r]);
      }
    }
#pragma unroll
    for (int ct = 0; ct < 8; ++ct) {
      int c = ct * 16 + sel;
      float bv = (MODE == 1) ? 0.f : bias[c];
#pragma unroll
      for (int j = 0; j < 4; ++j) {
        int r = t * 16 + kg * 4 + j;
        float v = acc[ct][j];
        if (MODE == 0) outH[r * H + c] = (_Float16)(v + bv);
        else if (MODE == 1) outH[r * H + c] = (_Float16)v;
        else outH[r * H + c] = (_Float16)((v + bv) * indeg[j]);
      }
    }
#pragma unroll
    for (int ks = 0; ks < 4; ++ks) afrag[ks] = anext[ks];
    t = tn;
  }
}

// ---- per-node gather of P rows + h update: hh = relu(hh + aggH + sum P[src])
// Quarter-wave (16 lanes x uint4 = 256B) reads one P row -> 4 edges per step,
// 4 loads (16 edges) in flight in the main loop. Accumulate in packed fp16
// (v_pk_add_f16); unpack to fp32 once per node. All shfls at wave-uniform
// control points (loop bounds depend only on uniform cnt).
__global__ __launch_bounds__(256) void agg_update(
    const _Float16* __restrict__ P, const int* __restrict__ rowp,
    const int* __restrict__ srcs, const _Float16* __restrict__ aggH,
    _Float16* hh, int N)
{
  int node = blockIdx.x * 4 + (threadIdx.x >> 6);
  if (node >= N) return;
  int lane = threadIdx.x & 63;
  int q = lane >> 4, li = lane & 15;
  const uint4* P4 = (const uint4*)P;
  h2 a0 = (h2)0, a1 = (h2)0, a2 = (h2)0, a3 = (h2)0;
  int e = rowp[node], end = rowp[node + 1];
  while (e < end) {
    int cnt = min(end - e, 64);          // wave-uniform
    int myS = (lane < cnt) ? srcs[e + lane] : 0;
    int j = 0;
    for (; j + 16 <= cnt; j += 16) {     // 16 edges, 4 loads in flight
      int s0 = __shfl(myS, j + q);
      int s1 = __shfl(myS, j + 4 + q);
      int s2 = __shfl(myS, j + 8 + q);
      int s3 = __shfl(myS, j + 12 + q);
      uint4 v0 = P4[s0 * 16 + li], v1 = P4[s1 * 16 + li];
      uint4 v2 = P4[s2 * 16 + li], v3 = P4[s3 * 16 + li];
      a0 += as_h2(v0.x) + as_h2(v1.x) + as_h2(v2.x) + as_h2(v3.x);
      a1 += as_h2(v0.y) + as_h2(v1.y) + as_h2(v2.y) + as_h2(v3.y);
      a2 += as_h2(v0.z) + as_h2(v1.z) + as_h2(v2.z) + as_h2(v3.z);
      a3 += as_h2(v0.w) + as_h2(v1.w) + as_h2(v2.w) + as_h2(v3.w);
    }
    for (; j + 8 <= cnt; j += 8) {       // 8 edges, 2 loads
      int s0 = __shfl(myS, j + q);
      int s1 = __shfl(myS, j + 4 + q);
      uint4 v0 = P4[s0 * 16 + li], v1 = P4[s1 * 16 + li];
      a0 += as_h2(v0.x) + as_h2(v1.x);
      a1 += as_h2(v0.y) + as_h2(v1.y);
      a2 += as_h2(v0.z) + as_h2(v1.z);
      a3 += as_h2(v0.w) + as_h2(v1.w);
    }
    for (; j < cnt; j += 4) {            // tail: predicated load, uniform shfl exec
      int jj = j + q;
      int s = __shfl(myS, (jj < cnt) ? jj : (cnt - 1));
      if (jj < cnt) {
        uint4 v = P4[s * 16 + li];
        a0 += as_h2(v.x); a1 += as_h2(v.y);
        a2 += as_h2(v.z); a3 += as_h2(v.w);
      }
    }
    e += cnt;
  }
  // unpack to fp32, reduce across the 4 quarter-waves
  float f[8] = { (float)a0[0], (float)a0[1], (float)a1[0], (float)a1[1],
                 (float)a2[0], (float)a2[1], (float)a3[0], (float)a3[1] };
#pragma unroll
  for (int i = 0; i < 8; ++i) {
    f[i] += __shfl_xor(f[i], 16);
    f[i] += __shfl_xor(f[i], 32);
  }
  if (q == 0) {
    int idx = node * 16 + li;            // row = 16 uint4
    uint4 hv = ((const uint4*)hh)[idx];
    uint4 av = ((const uint4*)aggH)[idx];
    union { _Float16 h[8]; uint4 u; } pk;
    unsigned hvs[4] = { hv.x, hv.y, hv.z, hv.w };
    unsigned avs[4] = { av.x, av.y, av.z, av.w };
#pragma unroll
    for (int i = 0; i < 4; ++i) {
      float r0 = fmaxf(u2f_lo(hvs[i]) + u2f_lo(avs[i]) + f[2 * i], 0.f);
      float r1 = fmaxf(u2f_hi(hvs[i]) + u2f_hi(avs[i]) + f[2 * i + 1], 0.f);
      pk.h[2 * i] = (_Float16)r0; pk.h[2 * i + 1] = (_Float16)r1;
    }
    ((uint4*)hh)[idx] = pk.u;
  }
}

// ---- mean pool (batch sorted): fp16 input, 4 row-substreams x 64 u32-cols
__global__ void pool_k(const _Float16* __restrict__ hh, const int* __restrict__ batch,
                       float* __restrict__ gsum, float* __restrict__ gcnt, int N)
{
  int t = threadIdx.x, c2 = t & 63, sub = t >> 6;
  int per = (N + gridDim.x - 1) / gridDim.x;
  int s = blockIdx.x * per;
  int e = s + per; if (e > N) e = N;
  const unsigned* hu = (const unsigned*)hh;
  float a0 = 0.f, a1 = 0.f; int cnt = 0, cur = -1;
  for (int n = s + sub; n < e; n += 4) {
    int b = batch[n];
    if (b != cur) {
      if (cur >= 0) {
        atomicAdd(&gsum[cur * H + c2 * 2], a0);
        atomicAdd(&gsum[cur * H + c2 * 2 + 1], a1);
        if (c2 == 0) atomicAdd(&gcnt[cur], (float)cnt);
      }
      a0 = 0.f; a1 = 0.f; cnt = 0; cur = b;
    }
    unsigned v = hu[n * 64 + c2];
    a0 += u2f_lo(v); a1 += u2f_hi(v); ++cnt;
  }
  if (cur >= 0) {
    atomicAdd(&gsum[cur * H + c2 * 2], a0);
    atomicAdd(&gsum[cur * H + c2 * 2 + 1], a1);
    if (c2 == 0) atomicAdd(&gcnt[cur], (float)cnt);
  }
}

__global__ void readout1(const float* __restrict__ gsum, const float* __restrict__ gcnt,
                         const float* __restrict__ W1, const float* __restrict__ b1,
                         float* __restrict__ hidden)
{
  int b = blockIdx.x, j = threadIdx.x;
  __shared__ float g[H];
  if (j < H) g[j] = gsum[b * H + j] / fmaxf(gcnt[b], 1.f);
  __syncthreads();
  float s = b1[j];
  for (int k = 0; k < H; ++k) s += g[k] * W1[k * HH2 + j];
  hidden[b * HH2 + j] = fmaxf(s, 0.f);
}

__global__ void readout2(const float* __restrict__ hidden, const float* __restrict__ W2,
                         const float* __restrict__ b2, float* __restrict__ out)
{
  int gid = blockIdx.x * 256 + threadIdx.x;
  int b = gid >> 11, m = gid & 2047;
  __shared__ float hs[HH2];
  hs[threadIdx.x] = hidden[b * HH2 + threadIdx.x];
  __syncthreads();
  float s = b2[m];
  for (int j = 0; j < HH2; ++j) s += hs[j] * W2[j * M_OUT + m];
  out[gid] = 6.283185307179586f / (1.f + expf(-s));
}

extern "C" void kernel_launch(void* const* d_in, const int* in_sizes, int n_in,
                              void* d_out, int out_size, void* d_ws, size_t ws_size,
                              hipStream_t stream) {
  const float* x       = (const float*)d_in[0];
  const int*   ei      = (const int*)d_in[1];
  const int*   batch   = (const int*)d_in[2];
  const float* W_embed = (const float*)d_in[3];
  const float* b_embed = (const float*)d_in[4];
  const float* Wm      = (const float*)d_in[5];
  const float* bm      = (const float*)d_in[6];
  const float* W1      = (const float*)d_in[7];
  const float* b1      = (const float*)d_in[8];
  const float* W2      = (const float*)d_in[9];
  const float* b2      = (const float*)d_in[10];
  float* out = (float*)d_out;

  const int N = in_sizes[0] / H;
  const int E = in_sizes[1] / 2;
  const int nbuck = (N + 127) >> 7;
  const int chunk = (E + CB - 1) / CB;

  char* p = (char*)d_ws;
  auto carve = [&](size_t bytes) { void* r = (void*)p; p += (bytes + 255) & ~(size_t)255; return r; };
  _Float16*  hh      = (_Float16*)carve((size_t)N * H * 2);
  _Float16*  aggH    = (_Float16*)carve((size_t)N * H * 2);
  _Float16*  Pbuf    = (_Float16*)carve((size_t)N * H * 2);
  int*       row_ptr = (int*)carve((size_t)(N + 1) * 4);
  int*       srcs    = (int*)carve((size_t)E * 4);
  unsigned*  pairs   = (unsigned*)carve((size_t)E * 4);
  int*       hist    = (int*)carve((size_t)CB * MAXBUCK * 4);
  int*       totals  = (int*)carve((size_t)(MAXBUCK + 1) * 4);
  int*       bbase   = (int*)carve((size_t)(MAXBUCK + 1) * 4);
  _Float16*  WtAll   = (_Float16*)carve(7 * 16384 * 2);
  float*     gsum    = (float*)carve(16 * H * 4);
  float*     gcnt    = (float*)carve(16 * 4);
  float*     hidden  = (float*)carve(16 * HH2 * 4);

  hipMemsetAsync(gsum, 0, 16 * H * 4, stream);
  hipMemsetAsync(gcnt, 0, 16 * 4, stream);

  prep_weights<<<(7 * 16384 + 255) / 256, 256, 0, stream>>>(W_embed, Wm, WtAll);

  // CSR build (atomic-free at global scope)
  hist_k<<<CB, 1024, 0, stream>>>(ei, E, chunk, hist, nbuck);
  scanb_k<<<nbuck, CB, 0, stream>>>(hist, totals, nbuck);
  scant_k<<<1, MAXBUCK, 0, stream>>>(totals, bbase, row_ptr, nbuck, E, N);
  scat_k<<<CB, 1024, 0, stream>>>(ei, E, chunk, hist, bbase, pairs, nbuck);
  build_k<<<nbuck, 256, 0, stream>>>(pairs, bbase, row_ptr, srcs, N);

  int ntiles = N / 16;
  gemm_k<0><<<512, 256, 0, stream>>>(nullptr, x, WtAll, b_embed, nullptr, hh, ntiles);
  for (int l = 0; l < 3; ++l) {
    gemm_k<1><<<512, 256, 0, stream>>>(hh, nullptr, WtAll + (1 + 2 * l) * 16384, nullptr, nullptr, Pbuf, ntiles);
    gemm_k<2><<<512, 256, 0, stream>>>(hh, nullptr, WtAll + (2 + 2 * l) * 16384, bm + l * H, row_ptr, aggH, ntiles);
    agg_update<<<(N + 3) / 4, 256, 0, stream>>>(Pbuf, row_ptr, srcs, aggH, hh, N);
  }
  pool_k<<<512, 256, 0, stream>>>(hh, batch, gsum, gcnt, N);
  readout1<<<16, HH2, 0, stream>>>(gsum, gcnt, W1, b1, hidden);
  readout2<<<16 * M_OUT / 256, 256, 0, stream>>>(hidden, W2, b2, out);
}